// Round 9
// baseline (967.385 us; speedup 1.0000x reference)
//
#include <hip/hip_runtime.h>
#include <hip/hip_bf16.h>

#define HIDDEN 2048
#define INNER  1024
#define NE     64
#define TOPK   8
#define NTOK   512

typedef float f32x4 __attribute__((ext_vector_type(4)));
typedef short bf16x8 __attribute__((ext_vector_type(8)));

static __device__ __forceinline__ unsigned short b16(float f) {
  return __builtin_bit_cast(unsigned short, __float2bfloat16(f));
}
static __device__ __forceinline__ unsigned int pk2(float lo, float hi) {
  return (unsigned)b16(lo) | ((unsigned)b16(hi) << 16);
}

// XCD-affinity decode: expert e -> XCD e&7 (dispatch assumed round-robin flat%8).
// flat = ((e>>3)*16 + c)*8 + (e&7); bijective for grid 1024.
static __device__ __forceinline__ void decode_ce(int flat, int& c, int& e) {
  int xcd = flat & 7, s = flat >> 3;
  c = s & 15;
  e = ((s >> 4) << 3) | xcd;
}

// ---- gating: xconv + gate dot + topk; last block does scan+scatter ----
__global__ __launch_bounds__(256) void gating_kernel(
    const float* __restrict__ x, const float* __restrict__ gw, const float* __restrict__ gb,
    int* __restrict__ ticket, int* __restrict__ counts, int* __restrict__ offsets,
    int* __restrict__ topk_e, float* __restrict__ topk_w,
    int* __restrict__ perm_tok, int* __restrict__ invpos,
    unsigned short* __restrict__ xb) {
  const int t = blockIdx.x;
  const int tid = threadIdx.x;
  const int lane = tid & 63, w = tid >> 6;

  // fused: x -> bf16
  {
    const float4* xi = (const float4*)(x + (size_t)t * HIDDEN);
    float4 v0 = xi[tid * 2], v1 = xi[tid * 2 + 1];
    ushort4 o0, o1;
    o0.x = b16(v0.x); o0.y = b16(v0.y); o0.z = b16(v0.z); o0.w = b16(v0.w);
    o1.x = b16(v1.x); o1.y = b16(v1.y); o1.z = b16(v1.z); o1.w = b16(v1.w);
    ushort4* xo = (ushort4*)(xb + (size_t)t * HIDDEN);
    xo[tid * 2] = o0; xo[tid * 2 + 1] = o1;
  }

  // gate logits: one quad per expert, 64 B contiguous per instruction per row
  const int e = tid >> 2, seg = tid & 3;
  const f32x4* gr = (const f32x4*)(gw + (size_t)e * HIDDEN);
  const f32x4* xr = (const f32x4*)(x + (size_t)t * HIDDEN);
  float acc = 0.f;
  #pragma unroll 8
  for (int k = 0; k < 128; ++k) {
    int idx = k * 4 + seg;
    f32x4 a = xr[idx], b = gr[idx];
    acc += a.x * b.x + a.y * b.y + a.z * b.z + a.w * b.w;
  }
  acc += __shfl_xor(acc, 1);
  acc += __shfl_xor(acc, 2);
  __shared__ float sP[NE];
  if (seg == 0) sP[e] = acc;
  __syncthreads();

  __shared__ float sW[TOPK];
  __shared__ int   sE[TOPK];
  if (w == 0) {
    float logit = gb[lane] + sP[lane];
    float m = logit;
    #pragma unroll
    for (int off = 32; off; off >>= 1) m = fmaxf(m, __shfl_xor(m, off));
    float p = __expf(logit - m);
    float s = p;
    #pragma unroll
    for (int off = 32; off; off >>= 1) s += __shfl_xor(s, off);
    p /= s;
    float myp = p;
    #pragma unroll
    for (int k = 0; k < TOPK; ++k) {
      float v = myp; int ei = lane;
      #pragma unroll
      for (int off = 32; off; off >>= 1) {
        float v2 = __shfl_xor(v, off); int e2 = __shfl_xor(ei, off);
        if (v2 > v || (v2 == v && e2 < ei)) { v = v2; ei = e2; }
      }
      if (lane == 0) { sW[k] = v; sE[k] = ei; }
      if (lane == ei) myp = -1.0f;
    }
  }
  __syncthreads();
  if (tid < TOPK) {
    float ss = 0.f;
    #pragma unroll
    for (int k = 0; k < TOPK; ++k) ss += sW[k];
    topk_e[t * TOPK + tid] = sE[tid];
    topk_w[t * TOPK + tid] = sW[tid] / ss;
  }

  // last-block tail: histogram -> scan -> scatter
  __threadfence();
  __syncthreads();
  __shared__ int slast;
  if (tid == 0) {
    int old = atomicAdd(ticket, 1);
    slast = (old == (int)gridDim.x - 1);
  }
  __syncthreads();
  if (!slast) return;
  __threadfence();

  __shared__ int hcnt[NE], soff[NE], ccur[NE];
  if (tid < NE) hcnt[tid] = 0;
  __syncthreads();
  for (int i = tid; i < NTOK * TOPK; i += 256) atomicAdd(&hcnt[topk_e[i]], 1);
  __syncthreads();
  if (tid < NE) {
    int c = hcnt[tid];
    int s = c;
    #pragma unroll
    for (int off = 1; off < 64; off <<= 1) {
      int o = __shfl_up(s, off);
      if (tid >= off) s += o;
    }
    soff[tid] = s - c; ccur[tid] = 0;
    counts[tid] = c; offsets[tid] = s - c;
  }
  __syncthreads();
  for (int i = tid; i < NTOK * TOPK; i += 256) {
    int ee = topk_e[i];
    int p = atomicAdd(&ccur[ee], 1);
    int pos = soff[ee] + p;
    perm_tok[pos] = i >> 3;
    invpos[i] = pos;
  }
}

// ---- phase 1: act = gelu(x@w1g^T) * (x@w1u^T), tile 128M x (64 gate + 64 up) ----
__global__ __launch_bounds__(512, 4) void phase1_kernel(
    const unsigned short* __restrict__ xb, const float* __restrict__ w1,
    const int* __restrict__ offsets, const int* __restrict__ counts,
    const int* __restrict__ perm_tok, unsigned short* __restrict__ act) {
  int c, e;
  decode_ce(blockIdx.x, c, e);
  const int n_e = counts[e];
  if (n_e == 0) return;
  const int off = offsets[e];
  const int tid = threadIdx.x;
  const int lane = tid & 63, wave = tid >> 6;
  const int mat = wave >> 2;          // 0 = gate, 1 = up
  const int wm  = (wave & 3) * 32;

  // B staging: 16 lanes cover 256 B contiguous per row; rows r32 + p*32
  const int r32 = tid >> 4, l16 = tid & 15;
  const float* wg  = w1 + (size_t)e * (2 * INNER) * HIDDEN;
  const float* rp0 = wg + (size_t)(c * 64 + r32) * HIDDEN;
  const float* rp1 = rp0 + (size_t)32 * HIDDEN;
  const float* rp2 = rp0 + (size_t)INNER * HIDDEN;
  const float* rp3 = rp2 + (size_t)32 * HIDDEN;
  const int bidx0 = r32 * 16 + (((l16 >> 1) ^ (r32 & 7)) << 1) + (l16 & 1);  // uint2 units

  const int ar0 = tid >> 3, ar1 = (tid >> 3) + 64;
  const int as = tid & 7;
  const int sxa = as ^ (ar0 & 7);

  __shared__ uint4 smem[2][2][128 * 8];
  __shared__ int stok[128];
  float (*sU)[68] = (float(*)[68])&smem[0][0][0];

  for (int m0 = 0; m0 < n_e; m0 += 128) {
    __syncthreads();
    if (tid < 128) {
      int idx = m0 + tid;
      stok[tid] = perm_tok[off + (idx < n_e ? idx : n_e - 1)];
    }
    __syncthreads();

    uint4 va0, va1; f32x4 vB0, vB1, vB2, vB3;
    va0 = *((const uint4*)(xb + (size_t)stok[ar0] * HIDDEN) + as);
    va1 = *((const uint4*)(xb + (size_t)stok[ar1] * HIDDEN) + as);
    vB0 = *((const f32x4*)rp0 + l16);
    vB1 = *((const f32x4*)rp1 + l16);
    vB2 = *((const f32x4*)rp2 + l16);
    vB3 = *((const f32x4*)rp3 + l16);

    f32x4 acc[2][4];
    #pragma unroll
    for (int i = 0; i < 2; ++i)
      #pragma unroll
      for (int j = 0; j < 4; ++j) acc[i][j] = (f32x4)0.f;

    for (int k0 = 0; k0 < HIDDEN; k0 += 64) {
      const int cur = (k0 >> 6) & 1;
      smem[cur][0][ar0 * 8 + sxa] = va0;
      smem[cur][0][ar1 * 8 + sxa] = va1;
      {
        uint2* b2 = (uint2*)smem[cur][1];
        b2[bidx0]        = make_uint2(pk2(vB0.x, vB0.y), pk2(vB0.z, vB0.w));
        b2[bidx0 + 512]  = make_uint2(pk2(vB1.x, vB1.y), pk2(vB1.z, vB1.w));
        b2[bidx0 + 1024] = make_uint2(pk2(vB2.x, vB2.y), pk2(vB2.z, vB2.w));
        b2[bidx0 + 1536] = make_uint2(pk2(vB3.x, vB3.y), pk2(vB3.z, vB3.w));
      }
      __syncthreads();
      int k1 = k0 + 64;
      if (k1 < HIDDEN) {
        va0 = *((const uint4*)(xb + (size_t)stok[ar0] * HIDDEN + k1) + as);
        va1 = *((const uint4*)(xb + (size_t)stok[ar1] * HIDDEN + k1) + as);
        vB0 = *((const f32x4*)(rp0 + k1) + l16);
        vB1 = *((const f32x4*)(rp1 + k1) + l16);
        vB2 = *((const f32x4*)(rp2 + k1) + l16);
        vB3 = *((const f32x4*)(rp3 + k1) + l16);
      }
      #pragma unroll
      for (int ks = 0; ks < 2; ++ks) {
        const int u = ks * 4 + (lane >> 4);
        bf16x8 af[2], bfr[4];
        #pragma unroll
        for (int mi = 0; mi < 2; ++mi) {
          int r = wm + mi * 16 + (lane & 15);
          af[mi] = __builtin_bit_cast(bf16x8, smem[cur][0][r * 8 + (u ^ (r & 7))]);
        }
        #pragma unroll
        for (int ni = 0; ni < 4; ++ni) {
          int r = mat * 64 + ni * 16 + (lane & 15);
          bfr[ni] = __builtin_bit_cast(bf16x8, smem[cur][1][r * 8 + (u ^ (r & 7))]);
        }
        #pragma unroll
        for (int mi = 0; mi < 2; ++mi)
          #pragma unroll
          for (int ni = 0; ni < 4; ++ni)
            acc[mi][ni] = __builtin_amdgcn_mfma_f32_16x16x32_bf16(af[mi], bfr[ni], acc[mi][ni], 0, 0, 0);
      }
    }

    __syncthreads();
    if (mat == 1) {
      #pragma unroll
      for (int mi = 0; mi < 2; ++mi)
        #pragma unroll
        for (int ni = 0; ni < 4; ++ni)
          #pragma unroll
          for (int r4 = 0; r4 < 4; ++r4)
            sU[wm + mi * 16 + (lane >> 4) * 4 + r4][ni * 16 + (lane & 15)] = acc[mi][ni][r4];
    }
    __syncthreads();
    if (mat == 0) {
      #pragma unroll
      for (int mi = 0; mi < 2; ++mi)
        #pragma unroll
        for (int r4 = 0; r4 < 4; ++r4) {
          int mrow = wm + mi * 16 + (lane >> 4) * 4 + r4;
          int m = m0 + mrow;
          if (m < n_e) {
            unsigned short* arow = act + (size_t)(off + m) * INNER + c * 64;
            #pragma unroll
            for (int ni = 0; ni < 4; ++ni) {
              int col = ni * 16 + (lane & 15);
              float g = acc[mi][ni][r4];
              float uu = sU[mrow][col];
              float ge = g / (1.0f + __expf(-1.5957691216057308f * (g + 0.044715f * g * g * g)));
              arow[col] = b16(ge * uu);
            }
          }
        }
    }
  }
}

// ---- phase 2: ybuf[p] = act[p] @ w2[e]^T, tile 128M x 128N, plain stores ----
__global__ __launch_bounds__(512, 4) void phase2_kernel(
    const unsigned short* __restrict__ act, const float* __restrict__ w2,
    const int* __restrict__ offsets, const int* __restrict__ counts,
    float* __restrict__ ybuf) {
  int c, e;
  decode_ce(blockIdx.x, c, e);
  const int n_e = counts[e];
  if (n_e == 0) return;
  const int off = offsets[e];
  const int tid = threadIdx.x;
  const int lane = tid & 63, wave = tid >> 6;
  const int wm = (wave & 3) * 32;
  const int wn = (wave >> 2) * 64;

  const int r32 = tid >> 4, l16 = tid & 15;
  const float* rp0 = w2 + ((size_t)e * HIDDEN + c * 128 + r32) * INNER;
  const float* rp1 = rp0 + (size_t)32 * INNER;
  const float* rp2 = rp0 + (size_t)64 * INNER;
  const float* rp3 = rp0 + (size_t)96 * INNER;
  const int bidx0 = r32 * 16 + (((l16 >> 1) ^ (r32 & 7)) << 1) + (l16 & 1);

  const int ar0 = tid >> 3, ar1 = (tid >> 3) + 64;
  const int as = tid & 7;
  const int sxa = as ^ (ar0 & 7);

  __shared__ uint4 smem[2][2][128 * 8];

  for (int m0 = 0; m0 < n_e; m0 += 128) {
    const unsigned short* a0 = act + (size_t)(off + (m0 + ar0 < n_e ? m0 + ar0 : n_e - 1)) * INNER;
    const unsigned short* a1 = act + (size_t)(off + (m0 + ar1 < n_e ? m0 + ar1 : n_e - 1)) * INNER;

    uint4 va0, va1; f32x4 vB0, vB1, vB2, vB3;
    va0 = *((const uint4*)a0 + as);
    va1 = *((const uint4*)a1 + as);
    vB0 = *((const f32x4*)rp0 + l16);
    vB1 = *((const f32x4*)rp1 + l16);
    vB2 = *((const f32x4*)rp2 + l16);
    vB3 = *((const f32x4*)rp3 + l16);

    f32x4 acc[2][4];
    #pragma unroll
    for (int i = 0; i < 2; ++i)
      #pragma unroll
      for (int j = 0; j < 4; ++j) acc[i][j] = (f32x4)0.f;

    for (int k0 = 0; k0 < INNER; k0 += 64) {
      const int cur = (k0 >> 6) & 1;
      smem[cur][0][ar0 * 8 + sxa] = va0;
      smem[cur][0][ar1 * 8 + sxa] = va1;
      {
        uint2* b2 = (uint2*)smem[cur][1];
        b2[bidx0]        = make_uint2(pk2(vB0.x, vB0.y), pk2(vB0.z, vB0.w));
        b2[bidx0 + 512]  = make_uint2(pk2(vB1.x, vB1.y), pk2(vB1.z, vB1.w));
        b2[bidx0 + 1024] = make_uint2(pk2(vB2.x, vB2.y), pk2(vB2.z, vB2.w));
        b2[bidx0 + 1536] = make_uint2(pk2(vB3.x, vB3.y), pk2(vB3.z, vB3.w));
      }
      __syncthreads();
      int k1 = k0 + 64;
      if (k1 < INNER) {
        va0 = *((const uint4*)(a0 + k1) + as);
        va1 = *((const uint4*)(a1 + k1) + as);
        vB0 = *((const f32x4*)(rp0 + k1) + l16);
        vB1 = *((const f32x4*)(rp1 + k1) + l16);
        vB2 = *((const f32x4*)(rp2 + k1) + l16);
        vB3 = *((const f32x4*)(rp3 + k1) + l16);
      }
      #pragma unroll
      for (int ks = 0; ks < 2; ++ks) {
        const int u = ks * 4 + (lane >> 4);
        bf16x8 af[2], bfr[4];
        #pragma unroll
        for (int mi = 0; mi < 2; ++mi) {
          int r = wm + mi * 16 + (lane & 15);
          af[mi] = __builtin_bit_cast(bf16x8, smem[cur][0][r * 8 + (u ^ (r & 7))]);
        }
        #pragma unroll
        for (int ni = 0; ni < 4; ++ni) {
          int r = wn + ni * 16 + (lane & 15);
          bfr[ni] = __builtin_bit_cast(bf16x8, smem[cur][1][r * 8 + (u ^ (r & 7))]);
        }
        #pragma unroll
        for (int mi = 0; mi < 2; ++mi)
          #pragma unroll
          for (int ni = 0; ni < 4; ++ni)
            acc[mi][ni] = __builtin_amdgcn_mfma_f32_16x16x32_bf16(af[mi], bfr[ni], acc[mi][ni], 0, 0, 0);
      }
    }

    #pragma unroll
    for (int mi = 0; mi < 2; ++mi)
      #pragma unroll
      for (int r4 = 0; r4 < 4; ++r4) {
        int mrow = wm + mi * 16 + (lane >> 4) * 4 + r4;
        int m = m0 + mrow;
        if (m < n_e) {
          float* orow = ybuf + (size_t)(off + m) * HIDDEN + c * 128 + wn;
          #pragma unroll
          for (int ni = 0; ni < 4; ++ni)
            orow[ni * 16 + (lane & 15)] = acc[mi][ni][r4];
        }
      }
    __syncthreads();
  }
}

// ---- combine: out[t] = sum_k w_k * ybuf[invpos[t,k]] ----
__global__ __launch_bounds__(256) void combine_kernel(const float* __restrict__ ybuf,
                                                      const int* __restrict__ invpos,
                                                      const float* __restrict__ topk_w,
                                                      float* __restrict__ out) {
  int t = blockIdx.x;
  int tid = threadIdx.x;
  int col = tid * 8;
  f32x4 a0 = (f32x4)0.f, a1 = (f32x4)0.f;
  #pragma unroll
  for (int k = 0; k < TOPK; ++k) {
    int p = invpos[t * TOPK + k];
    float w = topk_w[t * TOPK + k];
    const f32x4* yr = (const f32x4*)(ybuf + (size_t)p * HIDDEN + col);
    f32x4 v0 = yr[0], v1 = yr[1];
    a0 += w * v0;
    a1 += w * v1;
  }
  f32x4* o = (f32x4*)(out + (size_t)t * HIDDEN + col);
  o[0] = a0; o[1] = a1;
}

extern "C" void kernel_launch(void* const* d_in, const int* in_sizes, int n_in,
                              void* d_out, int out_size, void* d_ws, size_t ws_size,
                              hipStream_t stream) {
  const float* x  = (const float*)d_in[0];
  const float* gw = (const float*)d_in[1];
  const float* gb = (const float*)d_in[2];
  const float* w1 = (const float*)d_in[3];
  const float* w2 = (const float*)d_in[4];
  float* out = (float*)d_out;

  char* ws = (char*)d_ws;
  int*   ticket   = (int*)(ws + 0x000);
  int*   counts   = (int*)(ws + 0x100);
  int*   offsets  = (int*)(ws + 0x200);
  int*   topk_e   = (int*)(ws + 0x1000);
  float* topk_w   = (float*)(ws + 0x5000);
  int*   perm_tok = (int*)(ws + 0x9000);
  int*   invpos   = (int*)(ws + 0xD000);
  unsigned short* xb  = (unsigned short*)(ws + 0x11000);    // 2 MB
  unsigned short* act = (unsigned short*)(ws + 0x220000);   // 8 MB
  float* ybuf         = (float*)(ws + 0xA20000);            // 32 MB

  hipMemsetAsync(ticket, 0, 0x40, stream);

  gating_kernel<<<NTOK, 256, 0, stream>>>(x, gw, gb, ticket, counts, offsets,
                                          topk_e, topk_w, perm_tok, invpos, xb);
  phase1_kernel<<<1024, 512, 0, stream>>>(xb, w1, offsets, counts, perm_tok, act);
  // DIFFERENTIAL PROBE: phase2 is idempotent (plain stores to ybuf, no input
  // mutation). Launch 5x; p2 = (dur_R9 - 448.5)/4. Everything else is
  // byte-identical to R7. Output unchanged.
  phase2_kernel<<<1024, 512, 0, stream>>>(act, w2, offsets, counts, ybuf);
  phase2_kernel<<<1024, 512, 0, stream>>>(act, w2, offsets, counts, ybuf);
  phase2_kernel<<<1024, 512, 0, stream>>>(act, w2, offsets, counts, ybuf);
  phase2_kernel<<<1024, 512, 0, stream>>>(act, w2, offsets, counts, ybuf);
  phase2_kernel<<<1024, 512, 0, stream>>>(act, w2, offsets, counts, ybuf);
  combine_kernel<<<NTOK, 256, 0, stream>>>(ybuf, invpos, topk_w, out);
}

// Round 10
// 498.514 us; speedup vs baseline: 1.9405x; 1.9405x over previous
//
#include <hip/hip_runtime.h>
#include <hip/hip_bf16.h>

#define HIDDEN 2048
#define INNER  1024
#define NE     64
#define TOPK   8
#define NTOK   512

typedef float f32x4 __attribute__((ext_vector_type(4)));
typedef short bf16x8 __attribute__((ext_vector_type(8)));

static __device__ __forceinline__ unsigned short b16(float f) {
  return __builtin_bit_cast(unsigned short, __float2bfloat16(f));
}
static __device__ __forceinline__ unsigned int pk2(float lo, float hi) {
  return (unsigned)b16(lo) | ((unsigned)b16(hi) << 16);
}

// XCD-affinity decode: expert e -> XCD e&7 (dispatch assumed round-robin flat%8).
static __device__ __forceinline__ void decode_ce(int flat, int& c, int& e) {
  int xcd = flat & 7, s = flat >> 3;
  c = s & 15;
  e = ((s >> 4) << 3) | xcd;
}

// ---- gating: xconv + gate dot + topk; last block does scan+scatter ----
__global__ __launch_bounds__(256) void gating_kernel(
    const float* __restrict__ x, const float* __restrict__ gw, const float* __restrict__ gb,
    int* __restrict__ ticket, int* __restrict__ counts, int* __restrict__ offsets,
    int* __restrict__ topk_e, float* __restrict__ topk_w,
    int* __restrict__ perm_tok, int* __restrict__ invpos,
    unsigned short* __restrict__ xb) {
  const int t = blockIdx.x;
  const int tid = threadIdx.x;
  const int lane = tid & 63, w = tid >> 6;

  {
    const float4* xi = (const float4*)(x + (size_t)t * HIDDEN);
    float4 v0 = xi[tid * 2], v1 = xi[tid * 2 + 1];
    ushort4 o0, o1;
    o0.x = b16(v0.x); o0.y = b16(v0.y); o0.z = b16(v0.z); o0.w = b16(v0.w);
    o1.x = b16(v1.x); o1.y = b16(v1.y); o1.z = b16(v1.z); o1.w = b16(v1.w);
    ushort4* xo = (ushort4*)(xb + (size_t)t * HIDDEN);
    xo[tid * 2] = o0; xo[tid * 2 + 1] = o1;
  }

  const int e = tid >> 2, seg = tid & 3;
  const f32x4* gr = (const f32x4*)(gw + (size_t)e * HIDDEN);
  const f32x4* xr = (const f32x4*)(x + (size_t)t * HIDDEN);
  float acc = 0.f;
  #pragma unroll 8
  for (int k = 0; k < 128; ++k) {
    int idx = k * 4 + seg;
    f32x4 a = xr[idx], b = gr[idx];
    acc += a.x * b.x + a.y * b.y + a.z * b.z + a.w * b.w;
  }
  acc += __shfl_xor(acc, 1);
  acc += __shfl_xor(acc, 2);
  __shared__ float sP[NE];
  if (seg == 0) sP[e] = acc;
  __syncthreads();

  __shared__ float sW[TOPK];
  __shared__ int   sE[TOPK];
  if (w == 0) {
    float logit = gb[lane] + sP[lane];
    float m = logit;
    #pragma unroll
    for (int off = 32; off; off >>= 1) m = fmaxf(m, __shfl_xor(m, off));
    float p = __expf(logit - m);
    float s = p;
    #pragma unroll
    for (int off = 32; off; off >>= 1) s += __shfl_xor(s, off);
    p /= s;
    float myp = p;
    #pragma unroll
    for (int k = 0; k < TOPK; ++k) {
      float v = myp; int ei = lane;
      #pragma unroll
      for (int off = 32; off; off >>= 1) {
        float v2 = __shfl_xor(v, off); int e2 = __shfl_xor(ei, off);
        if (v2 > v || (v2 == v && e2 < ei)) { v = v2; ei = e2; }
      }
      if (lane == 0) { sW[k] = v; sE[k] = ei; }
      if (lane == ei) myp = -1.0f;
    }
  }
  __syncthreads();
  if (tid < TOPK) {
    float ss = 0.f;
    #pragma unroll
    for (int k = 0; k < TOPK; ++k) ss += sW[k];
    topk_e[t * TOPK + tid] = sE[tid];
    topk_w[t * TOPK + tid] = sW[tid] / ss;
  }

  __threadfence();
  __syncthreads();
  __shared__ int slast;
  if (tid == 0) {
    int old = atomicAdd(ticket, 1);
    slast = (old == (int)gridDim.x - 1);
  }
  __syncthreads();
  if (!slast) return;
  __threadfence();

  __shared__ int hcnt[NE], soff[NE], ccur[NE];
  if (tid < NE) hcnt[tid] = 0;
  __syncthreads();
  for (int i = tid; i < NTOK * TOPK; i += 256) atomicAdd(&hcnt[topk_e[i]], 1);
  __syncthreads();
  if (tid < NE) {
    int c = hcnt[tid];
    int s = c;
    #pragma unroll
    for (int off = 1; off < 64; off <<= 1) {
      int o = __shfl_up(s, off);
      if (tid >= off) s += o;
    }
    soff[tid] = s - c; ccur[tid] = 0;
    counts[tid] = c; offsets[tid] = s - c;
  }
  __syncthreads();
  for (int i = tid; i < NTOK * TOPK; i += 256) {
    int ee = topk_e[i];
    int p = atomicAdd(&ccur[ee], 1);
    int pos = soff[ee] + p;
    perm_tok[pos] = i >> 3;
    invpos[i] = pos;
  }
}

// ---- phase 1: act = gelu(x@w1g^T) * (x@w1u^T) ----
// depth-2 prefetch on w1 stream, raw s_barrier (no vmcnt drain), 1 barrier/k-step
__global__ __launch_bounds__(512, 4) void phase1_kernel(
    const unsigned short* __restrict__ xb, const float* __restrict__ w1,
    const int* __restrict__ offsets, const int* __restrict__ counts,
    const int* __restrict__ perm_tok, unsigned short* __restrict__ act) {
  int c, e;
  decode_ce(blockIdx.x, c, e);
  const int n_e = counts[e];
  if (n_e == 0) return;
  const int off = offsets[e];
  const int tid = threadIdx.x;
  const int lane = tid & 63, wave = tid >> 6;
  const int mat = wave >> 2;          // 0 = gate, 1 = up
  const int wm  = (wave & 3) * 32;

  const int r32 = tid >> 4, l16 = tid & 15;
  const float* wg  = w1 + (size_t)e * (2 * INNER) * HIDDEN;
  const float* rp0 = wg + (size_t)(c * 64 + r32) * HIDDEN;
  const float* rp1 = rp0 + (size_t)32 * HIDDEN;
  const float* rp2 = rp0 + (size_t)INNER * HIDDEN;
  const float* rp3 = rp2 + (size_t)32 * HIDDEN;
  const int bidx0 = r32 * 16 + (((l16 >> 1) ^ (r32 & 7)) << 1) + (l16 & 1);

  const int ar0 = tid >> 3, ar1 = (tid >> 3) + 64;
  const int as = tid & 7;
  const int sxa = as ^ (ar0 & 7);

  __shared__ uint4 smem[2][2][128 * 8];
  __shared__ int stok[128];
  float (*sU)[68] = (float(*)[68])&smem[0][0][0];

  for (int m0 = 0; m0 < n_e; m0 += 128) {
    __syncthreads();
    if (tid < 128) {
      int idx = m0 + tid;
      stok[tid] = perm_tok[off + (idx < n_e ? idx : n_e - 1)];
    }
    __syncthreads();

    const unsigned short* xrow0 = xb + (size_t)stok[ar0] * HIDDEN;
    const unsigned short* xrow1 = xb + (size_t)stok[ar1] * HIDDEN;

    // prologue: A(k0), B(k0) and B(k0+64)
    uint4 va0 = *((const uint4*)xrow0 + as);
    uint4 va1 = *((const uint4*)xrow1 + as);
    f32x4 vA0 = *((const f32x4*)rp0 + l16);
    f32x4 vA1 = *((const f32x4*)rp1 + l16);
    f32x4 vA2 = *((const f32x4*)rp2 + l16);
    f32x4 vA3 = *((const f32x4*)rp3 + l16);
    f32x4 vC0 = *((const f32x4*)(rp0 + 64) + l16);
    f32x4 vC1 = *((const f32x4*)(rp1 + 64) + l16);
    f32x4 vC2 = *((const f32x4*)(rp2 + 64) + l16);
    f32x4 vC3 = *((const f32x4*)(rp3 + 64) + l16);

    f32x4 acc[2][4];
    #pragma unroll
    for (int i = 0; i < 2; ++i)
      #pragma unroll
      for (int j = 0; j < 4; ++j) acc[i][j] = (f32x4)0.f;

#define P1_STEP(K0, CUR, B0, B1, B2, B3)                                        \
    {                                                                           \
      smem[CUR][0][ar0 * 8 + sxa] = va0;                                        \
      smem[CUR][0][ar1 * 8 + sxa] = va1;                                        \
      uint2* bb = (uint2*)smem[CUR][1];                                         \
      bb[bidx0]        = make_uint2(pk2(B0.x, B0.y), pk2(B0.z, B0.w));          \
      bb[bidx0 + 512]  = make_uint2(pk2(B1.x, B1.y), pk2(B1.z, B1.w));          \
      bb[bidx0 + 1024] = make_uint2(pk2(B2.x, B2.y), pk2(B2.z, B2.w));          \
      bb[bidx0 + 1536] = make_uint2(pk2(B3.x, B3.y), pk2(B3.z, B3.w));          \
      asm volatile("s_waitcnt lgkmcnt(0)" ::: "memory");                        \
      __builtin_amdgcn_s_barrier();                                             \
      if ((K0) + 64 < HIDDEN) {                                                 \
        va0 = *((const uint4*)(xrow0 + (K0) + 64) + as);                        \
        va1 = *((const uint4*)(xrow1 + (K0) + 64) + as);                        \
      }                                                                         \
      if ((K0) + 128 < HIDDEN) {                                                \
        B0 = *((const f32x4*)(rp0 + (K0) + 128) + l16);                         \
        B1 = *((const f32x4*)(rp1 + (K0) + 128) + l16);                         \
        B2 = *((const f32x4*)(rp2 + (K0) + 128) + l16);                         \
        B3 = *((const f32x4*)(rp3 + (K0) + 128) + l16);                         \
      }                                                                         \
      _Pragma("unroll")                                                         \
      for (int ks = 0; ks < 2; ++ks) {                                          \
        const int u = ks * 4 + (lane >> 4);                                     \
        bf16x8 af[2], bfr[4];                                                   \
        _Pragma("unroll")                                                       \
        for (int mi = 0; mi < 2; ++mi) {                                        \
          int r = wm + mi * 16 + (lane & 15);                                   \
          af[mi] = __builtin_bit_cast(bf16x8, smem[CUR][0][r * 8 + (u ^ (r & 7))]); \
        }                                                                       \
        _Pragma("unroll")                                                       \
        for (int ni = 0; ni < 4; ++ni) {                                        \
          int r = mat * 64 + ni * 16 + (lane & 15);                             \
          bfr[ni] = __builtin_bit_cast(bf16x8, smem[CUR][1][r * 8 + (u ^ (r & 7))]); \
        }                                                                       \
        _Pragma("unroll")                                                       \
        for (int mi = 0; mi < 2; ++mi)                                          \
          _Pragma("unroll")                                                     \
          for (int ni = 0; ni < 4; ++ni)                                        \
            acc[mi][ni] = __builtin_amdgcn_mfma_f32_16x16x32_bf16(af[mi], bfr[ni], acc[mi][ni], 0, 0, 0); \
      }                                                                         \
    }

    for (int k0 = 0; k0 < HIDDEN; k0 += 128) {
      P1_STEP(k0, 0, vA0, vA1, vA2, vA3)
      P1_STEP(k0 + 64, 1, vC0, vC1, vC2, vC3)
    }
#undef P1_STEP

    __syncthreads();
    if (mat == 1) {
      #pragma unroll
      for (int mi = 0; mi < 2; ++mi)
        #pragma unroll
        for (int ni = 0; ni < 4; ++ni)
          #pragma unroll
          for (int r4 = 0; r4 < 4; ++r4)
            sU[wm + mi * 16 + (lane >> 4) * 4 + r4][ni * 16 + (lane & 15)] = acc[mi][ni][r4];
    }
    __syncthreads();
    if (mat == 0) {
      #pragma unroll
      for (int mi = 0; mi < 2; ++mi)
        #pragma unroll
        for (int r4 = 0; r4 < 4; ++r4) {
          int mrow = wm + mi * 16 + (lane >> 4) * 4 + r4;
          int m = m0 + mrow;
          if (m < n_e) {
            unsigned short* arow = act + (size_t)(off + m) * INNER + c * 64;
            #pragma unroll
            for (int ni = 0; ni < 4; ++ni) {
              int col = ni * 16 + (lane & 15);
              float g = acc[mi][ni][r4];
              float uu = sU[mrow][col];
              float ge = g / (1.0f + __expf(-1.5957691216057308f * (g + 0.044715f * g * g * g)));
              arow[col] = b16(ge * uu);
            }
          }
        }
    }
  }
}

// ---- phase 2: ybuf[p] = act[p] @ w2[e]^T ----
// depth-2 prefetch on w2 stream, raw s_barrier, 1 barrier/k-step
__global__ __launch_bounds__(512, 4) void phase2_kernel(
    const unsigned short* __restrict__ act, const float* __restrict__ w2,
    const int* __restrict__ offsets, const int* __restrict__ counts,
    float* __restrict__ ybuf) {
  int c, e;
  decode_ce(blockIdx.x, c, e);
  const int n_e = counts[e];
  if (n_e == 0) return;
  const int off = offsets[e];
  const int tid = threadIdx.x;
  const int lane = tid & 63, wave = tid >> 6;
  const int wm = (wave & 3) * 32;
  const int wn = (wave >> 2) * 64;

  const int r32 = tid >> 4, l16 = tid & 15;
  const float* rp0 = w2 + ((size_t)e * HIDDEN + c * 128 + r32) * INNER;
  const float* rp1 = rp0 + (size_t)32 * INNER;
  const float* rp2 = rp0 + (size_t)64 * INNER;
  const float* rp3 = rp0 + (size_t)96 * INNER;
  const int bidx0 = r32 * 16 + (((l16 >> 1) ^ (r32 & 7)) << 1) + (l16 & 1);

  const int ar0 = tid >> 3, ar1 = (tid >> 3) + 64;
  const int as = tid & 7;
  const int sxa = as ^ (ar0 & 7);

  __shared__ uint4 smem[2][2][128 * 8];

  for (int m0 = 0; m0 < n_e; m0 += 128) {
    const unsigned short* a0 = act + (size_t)(off + (m0 + ar0 < n_e ? m0 + ar0 : n_e - 1)) * INNER;
    const unsigned short* a1 = act + (size_t)(off + (m0 + ar1 < n_e ? m0 + ar1 : n_e - 1)) * INNER;

    uint4 va0 = *((const uint4*)a0 + as);
    uint4 va1 = *((const uint4*)a1 + as);
    f32x4 vA0 = *((const f32x4*)rp0 + l16);
    f32x4 vA1 = *((const f32x4*)rp1 + l16);
    f32x4 vA2 = *((const f32x4*)rp2 + l16);
    f32x4 vA3 = *((const f32x4*)rp3 + l16);
    f32x4 vC0 = *((const f32x4*)(rp0 + 64) + l16);
    f32x4 vC1 = *((const f32x4*)(rp1 + 64) + l16);
    f32x4 vC2 = *((const f32x4*)(rp2 + 64) + l16);
    f32x4 vC3 = *((const f32x4*)(rp3 + 64) + l16);

    f32x4 acc[2][4];
    #pragma unroll
    for (int i = 0; i < 2; ++i)
      #pragma unroll
      for (int j = 0; j < 4; ++j) acc[i][j] = (f32x4)0.f;

#define P2_STEP(K0, CUR, B0, B1, B2, B3)                                        \
    {                                                                           \
      smem[CUR][0][ar0 * 8 + sxa] = va0;                                        \
      smem[CUR][0][ar1 * 8 + sxa] = va1;                                        \
      uint2* bb = (uint2*)smem[CUR][1];                                         \
      bb[bidx0]        = make_uint2(pk2(B0.x, B0.y), pk2(B0.z, B0.w));          \
      bb[bidx0 + 512]  = make_uint2(pk2(B1.x, B1.y), pk2(B1.z, B1.w));          \
      bb[bidx0 + 1024] = make_uint2(pk2(B2.x, B2.y), pk2(B2.z, B2.w));          \
      bb[bidx0 + 1536] = make_uint2(pk2(B3.x, B3.y), pk2(B3.z, B3.w));          \
      asm volatile("s_waitcnt lgkmcnt(0)" ::: "memory");                        \
      __builtin_amdgcn_s_barrier();                                             \
      if ((K0) + 64 < INNER) {                                                  \
        va0 = *((const uint4*)(a0 + (K0) + 64) + as);                           \
        va1 = *((const uint4*)(a1 + (K0) + 64) + as);                           \
      }                                                                         \
      if ((K0) + 128 < INNER) {                                                 \
        B0 = *((const f32x4*)(rp0 + (K0) + 128) + l16);                         \
        B1 = *((const f32x4*)(rp1 + (K0) + 128) + l16);                         \
        B2 = *((const f32x4*)(rp2 + (K0) + 128) + l16);                         \
        B3 = *((const f32x4*)(rp3 + (K0) + 128) + l16);                         \
      }                                                                         \
      _Pragma("unroll")                                                         \
      for (int ks = 0; ks < 2; ++ks) {                                          \
        const int u = ks * 4 + (lane >> 4);                                     \
        bf16x8 af[2], bfr[4];                                                   \
        _Pragma("unroll")                                                       \
        for (int mi = 0; mi < 2; ++mi) {                                        \
          int r = wm + mi * 16 + (lane & 15);                                   \
          af[mi] = __builtin_bit_cast(bf16x8, smem[CUR][0][r * 8 + (u ^ (r & 7))]); \
        }                                                                       \
        _Pragma("unroll")                                                       \
        for (int ni = 0; ni < 4; ++ni) {                                        \
          int r = wn + ni * 16 + (lane & 15);                                   \
          bfr[ni] = __builtin_bit_cast(bf16x8, smem[CUR][1][r * 8 + (u ^ (r & 7))]); \
        }                                                                       \
        _Pragma("unroll")                                                       \
        for (int mi = 0; mi < 2; ++mi)                                          \
          _Pragma("unroll")                                                     \
          for (int ni = 0; ni < 4; ++ni)                                        \
            acc[mi][ni] = __builtin_amdgcn_mfma_f32_16x16x32_bf16(af[mi], bfr[ni], acc[mi][ni], 0, 0, 0); \
      }                                                                         \
    }

    for (int k0 = 0; k0 < INNER; k0 += 128) {
      P2_STEP(k0, 0, vA0, vA1, vA2, vA3)
      P2_STEP(k0 + 64, 1, vC0, vC1, vC2, vC3)
    }
#undef P2_STEP

    #pragma unroll
    for (int mi = 0; mi < 2; ++mi)
      #pragma unroll
      for (int r4 = 0; r4 < 4; ++r4) {
        int mrow = wm + mi * 16 + (lane >> 4) * 4 + r4;
        int m = m0 + mrow;
        if (m < n_e) {
          float* orow = ybuf + (size_t)(off + m) * HIDDEN + c * 128 + wn;
          #pragma unroll
          for (int ni = 0; ni < 4; ++ni)
            orow[ni * 16 + (lane & 15)] = acc[mi][ni][r4];
        }
      }
    __syncthreads();
  }
}

// ---- combine: out[t] = sum_k w_k * ybuf[invpos[t,k]] ----
__global__ __launch_bounds__(256) void combine_kernel(const float* __restrict__ ybuf,
                                                      const int* __restrict__ invpos,
                                                      const float* __restrict__ topk_w,
                                                      float* __restrict__ out) {
  int t = blockIdx.x;
  int tid = threadIdx.x;
  int col = tid * 8;
  f32x4 a0 = (f32x4)0.f, a1 = (f32x4)0.f;
  #pragma unroll
  for (int k = 0; k < TOPK; ++k) {
    int p = invpos[t * TOPK + k];
    float w = topk_w[t * TOPK + k];
    const f32x4* yr = (const f32x4*)(ybuf + (size_t)p * HIDDEN + col);
    f32x4 v0 = yr[0], v1 = yr[1];
    a0 += w * v0;
    a1 += w * v1;
  }
  f32x4* o = (f32x4*)(out + (size_t)t * HIDDEN + col);
  o[0] = a0; o[1] = a1;
}

extern "C" void kernel_launch(void* const* d_in, const int* in_sizes, int n_in,
                              void* d_out, int out_size, void* d_ws, size_t ws_size,
                              hipStream_t stream) {
  const float* x  = (const float*)d_in[0];
  const float* gw = (const float*)d_in[1];
  const float* gb = (const float*)d_in[2];
  const float* w1 = (const float*)d_in[3];
  const float* w2 = (const float*)d_in[4];
  float* out = (float*)d_out;

  char* ws = (char*)d_ws;
  int*   ticket   = (int*)(ws + 0x000);
  int*   counts   = (int*)(ws + 0x100);
  int*   offsets  = (int*)(ws + 0x200);
  int*   topk_e   = (int*)(ws + 0x1000);
  float* topk_w   = (float*)(ws + 0x5000);
  int*   perm_tok = (int*)(ws + 0x9000);
  int*   invpos   = (int*)(ws + 0xD000);
  unsigned short* xb  = (unsigned short*)(ws + 0x11000);    // 2 MB
  unsigned short* act = (unsigned short*)(ws + 0x220000);   // 8 MB
  float* ybuf         = (float*)(ws + 0xA20000);            // 32 MB

  hipMemsetAsync(ticket, 0, 0x40, stream);

  gating_kernel<<<NTOK, 256, 0, stream>>>(x, gw, gb, ticket, counts, offsets,
                                          topk_e, topk_w, perm_tok, invpos, xb);
  phase1_kernel<<<1024, 512, 0, stream>>>(xb, w1, offsets, counts, perm_tok, act);
  phase2_kernel<<<1024, 512, 0, stream>>>(act, w2, offsets, counts, ybuf);
  combine_kernel<<<NTOK, 256, 0, stream>>>(ybuf, invpos, topk_w, out);
}

// Round 11
// 440.690 us; speedup vs baseline: 2.1952x; 1.1312x over previous
//
#include <hip/hip_runtime.h>
#include <hip/hip_bf16.h>

#define HIDDEN 2048
#define INNER  1024
#define NE     64
#define TOPK   8
#define NTOK   512

typedef float f32x4 __attribute__((ext_vector_type(4)));
typedef short bf16x8 __attribute__((ext_vector_type(8)));

static __device__ __forceinline__ unsigned short b16(float f) {
  return __builtin_bit_cast(unsigned short, __float2bfloat16(f));
}
static __device__ __forceinline__ unsigned int pk2(float lo, float hi) {
  return (unsigned)b16(lo) | ((unsigned)b16(hi) << 16);
}

// XCD-affinity decode for grid 2048: expert e -> XCD e&7.
// flat = (((e>>3)*32) + c)*8 + (e&7), c in [0,32).
static __device__ __forceinline__ void decode_ce32(int flat, int& c, int& e) {
  int xcd = flat & 7, s = flat >> 3;
  c = s & 31;
  e = ((s >> 5) << 3) | xcd;
}

// ---- gating: xconv + gate dot + topk; last block does scan+scatter ----
__global__ __launch_bounds__(256) void gating_kernel(
    const float* __restrict__ x, const float* __restrict__ gw, const float* __restrict__ gb,
    int* __restrict__ ticket, int* __restrict__ counts, int* __restrict__ offsets,
    int* __restrict__ topk_e, float* __restrict__ topk_w,
    int* __restrict__ perm_tok, int* __restrict__ invpos,
    unsigned short* __restrict__ xb) {
  const int t = blockIdx.x;
  const int tid = threadIdx.x;
  const int lane = tid & 63, w = tid >> 6;

  {
    const float4* xi = (const float4*)(x + (size_t)t * HIDDEN);
    float4 v0 = xi[tid * 2], v1 = xi[tid * 2 + 1];
    ushort4 o0, o1;
    o0.x = b16(v0.x); o0.y = b16(v0.y); o0.z = b16(v0.z); o0.w = b16(v0.w);
    o1.x = b16(v1.x); o1.y = b16(v1.y); o1.z = b16(v1.z); o1.w = b16(v1.w);
    ushort4* xo = (ushort4*)(xb + (size_t)t * HIDDEN);
    xo[tid * 2] = o0; xo[tid * 2 + 1] = o1;
  }

  const int e = tid >> 2, seg = tid & 3;
  const f32x4* gr = (const f32x4*)(gw + (size_t)e * HIDDEN);
  const f32x4* xr = (const f32x4*)(x + (size_t)t * HIDDEN);
  float acc = 0.f;
  #pragma unroll 8
  for (int k = 0; k < 128; ++k) {
    int idx = k * 4 + seg;
    f32x4 a = xr[idx], b = gr[idx];
    acc += a.x * b.x + a.y * b.y + a.z * b.z + a.w * b.w;
  }
  acc += __shfl_xor(acc, 1);
  acc += __shfl_xor(acc, 2);
  __shared__ float sP[NE];
  if (seg == 0) sP[e] = acc;
  __syncthreads();

  __shared__ float sW[TOPK];
  __shared__ int   sE[TOPK];
  if (w == 0) {
    float logit = gb[lane] + sP[lane];
    float m = logit;
    #pragma unroll
    for (int off = 32; off; off >>= 1) m = fmaxf(m, __shfl_xor(m, off));
    float p = __expf(logit - m);
    float s = p;
    #pragma unroll
    for (int off = 32; off; off >>= 1) s += __shfl_xor(s, off);
    p /= s;
    float myp = p;
    #pragma unroll
    for (int k = 0; k < TOPK; ++k) {
      float v = myp; int ei = lane;
      #pragma unroll
      for (int off = 32; off; off >>= 1) {
        float v2 = __shfl_xor(v, off); int e2 = __shfl_xor(ei, off);
        if (v2 > v || (v2 == v && e2 < ei)) { v = v2; ei = e2; }
      }
      if (lane == 0) { sW[k] = v; sE[k] = ei; }
      if (lane == ei) myp = -1.0f;
    }
  }
  __syncthreads();
  if (tid < TOPK) {
    float ss = 0.f;
    #pragma unroll
    for (int k = 0; k < TOPK; ++k) ss += sW[k];
    topk_e[t * TOPK + tid] = sE[tid];
    topk_w[t * TOPK + tid] = sW[tid] / ss;
  }

  __threadfence();
  __syncthreads();
  __shared__ int slast;
  if (tid == 0) {
    int old = atomicAdd(ticket, 1);
    slast = (old == (int)gridDim.x - 1);
  }
  __syncthreads();
  if (!slast) return;
  __threadfence();

  __shared__ int hcnt[NE], soff[NE], ccur[NE];
  if (tid < NE) hcnt[tid] = 0;
  __syncthreads();
  for (int i = tid; i < NTOK * TOPK; i += 256) atomicAdd(&hcnt[topk_e[i]], 1);
  __syncthreads();
  if (tid < NE) {
    int c = hcnt[tid];
    int s = c;
    #pragma unroll
    for (int off = 1; off < 64; off <<= 1) {
      int o = __shfl_up(s, off);
      if (tid >= off) s += o;
    }
    soff[tid] = s - c; ccur[tid] = 0;
    counts[tid] = c; offsets[tid] = s - c;
  }
  __syncthreads();
  for (int i = tid; i < NTOK * TOPK; i += 256) {
    int ee = topk_e[i];
    int p = atomicAdd(&ccur[ee], 1);
    int pos = soff[ee] + p;
    perm_tok[pos] = i >> 3;
    invpos[i] = pos;
  }
}

// ---- phase 1: act = gelu(x@w1g^T) * (x@w1u^T) ----
// 256 threads, tile 128M x 32N(gate)+32N(up), BK=64, dbuf LDS 48KB -> 3 blocks/CU
// waves: mat = wave>>1 (0=gate,1=up), wm = (wave&1)*64
__global__ __launch_bounds__(256, 3) void phase1_kernel(
    const unsigned short* __restrict__ xb, const float* __restrict__ w1,
    const int* __restrict__ offsets, const int* __restrict__ counts,
    const int* __restrict__ perm_tok, unsigned short* __restrict__ act) {
  int c, e;
  decode_ce32(blockIdx.x, c, e);
  const int n_e = counts[e];
  if (n_e == 0) return;
  const int off = offsets[e];
  const int tid = threadIdx.x;
  const int lane = tid & 63, wave = tid >> 6;
  const int u2 = lane >> 4, l15 = lane & 15;
  const int mat = wave >> 1;
  const int wm  = (wave & 1) * 64;

  // B staging: rows r16(gate lo), r16+16(gate hi), r16+32(up lo), r16+48(up hi)
  const int r16 = tid >> 4, l16 = tid & 15;
  const float* wg  = w1 + (size_t)e * (2 * INNER) * HIDDEN;
  const float* rp0 = wg + (size_t)(c * 32 + r16) * HIDDEN;
  const float* rp1 = rp0 + (size_t)16 * HIDDEN;
  const float* rp2 = wg + (size_t)(INNER + c * 32 + r16) * HIDDEN;
  const float* rp3 = rp2 + (size_t)16 * HIDDEN;
  const int bidx0 = r16 * 16 + (((l16 >> 1) ^ (r16 & 7)) << 1) + (l16 & 1);  // uint2 units

  // A staging: rows ar, ar+32, ar+64, ar+96; slot as
  const int ar = tid >> 3, as = tid & 7;
  const int sxa = as ^ (ar & 7);

  // smem[buf]: A = [0,1024) uint4 (16KB), B = [1024,1536) (8KB)
  __shared__ uint4 smem[2][1536];
  __shared__ int stok[128];
  float (*sU)[36] = (float(*)[36])&smem[0][0];   // 18KB, epilogue only

  for (int m0 = 0; m0 < n_e; m0 += 128) {
    __syncthreads();
    if (tid < 128) {
      int idx = m0 + tid;
      stok[tid] = perm_tok[off + (idx < n_e ? idx : n_e - 1)];
    }
    __syncthreads();

    const unsigned short* xr0 = xb + (size_t)stok[ar] * HIDDEN;
    const unsigned short* xr1 = xb + (size_t)stok[ar + 32] * HIDDEN;
    const unsigned short* xr2 = xb + (size_t)stok[ar + 64] * HIDDEN;
    const unsigned short* xr3 = xb + (size_t)stok[ar + 96] * HIDDEN;

    uint4 va0 = *((const uint4*)xr0 + as);
    uint4 va1 = *((const uint4*)xr1 + as);
    uint4 va2 = *((const uint4*)xr2 + as);
    uint4 va3 = *((const uint4*)xr3 + as);
    f32x4 vB0 = *((const f32x4*)rp0 + l16);
    f32x4 vB1 = *((const f32x4*)rp1 + l16);
    f32x4 vB2 = *((const f32x4*)rp2 + l16);
    f32x4 vB3 = *((const f32x4*)rp3 + l16);

    f32x4 acc[4][2];
    #pragma unroll
    for (int i = 0; i < 4; ++i)
      #pragma unroll
      for (int j = 0; j < 2; ++j) acc[i][j] = (f32x4)0.f;

    for (int k0 = 0; k0 < HIDDEN; k0 += 64) {
      const int cur = (k0 >> 6) & 1;
      uint4* A = smem[cur];
      A[ar * 8 + sxa]          = va0;
      A[(ar + 32) * 8 + sxa]   = va1;
      A[(ar + 64) * 8 + sxa]   = va2;
      A[(ar + 96) * 8 + sxa]   = va3;
      {
        uint2* bb = (uint2*)(smem[cur] + 1024);
        bb[bidx0]       = make_uint2(pk2(vB0.x, vB0.y), pk2(vB0.z, vB0.w));
        bb[bidx0 + 256] = make_uint2(pk2(vB1.x, vB1.y), pk2(vB1.z, vB1.w));
        bb[bidx0 + 512] = make_uint2(pk2(vB2.x, vB2.y), pk2(vB2.z, vB2.w));
        bb[bidx0 + 768] = make_uint2(pk2(vB3.x, vB3.y), pk2(vB3.z, vB3.w));
      }
      __syncthreads();
      int k1 = k0 + 64;
      if (k1 < HIDDEN) {
        va0 = *((const uint4*)(xr0 + k1) + as);
        va1 = *((const uint4*)(xr1 + k1) + as);
        va2 = *((const uint4*)(xr2 + k1) + as);
        va3 = *((const uint4*)(xr3 + k1) + as);
        vB0 = *((const f32x4*)(rp0 + k1) + l16);
        vB1 = *((const f32x4*)(rp1 + k1) + l16);
        vB2 = *((const f32x4*)(rp2 + k1) + l16);
        vB3 = *((const f32x4*)(rp3 + k1) + l16);
      }
      const uint4* Bq = smem[cur] + 1024;
      #pragma unroll
      for (int ks = 0; ks < 2; ++ks) {
        const int u = ks * 4 + u2;
        bf16x8 af[4], bfr[2];
        #pragma unroll
        for (int mi = 0; mi < 4; ++mi) {
          int r = wm + mi * 16 + l15;
          af[mi] = __builtin_bit_cast(bf16x8, A[r * 8 + (u ^ (r & 7))]);
        }
        #pragma unroll
        for (int ni = 0; ni < 2; ++ni) {
          int r = mat * 32 + ni * 16 + l15;
          bfr[ni] = __builtin_bit_cast(bf16x8, Bq[r * 8 + (u ^ (r & 7))]);
        }
        #pragma unroll
        for (int mi = 0; mi < 4; ++mi)
          #pragma unroll
          for (int ni = 0; ni < 2; ++ni)
            acc[mi][ni] = __builtin_amdgcn_mfma_f32_16x16x32_bf16(af[mi], bfr[ni], acc[mi][ni], 0, 0, 0);
      }
    }

    __syncthreads();
    if (mat == 1) {
      #pragma unroll
      for (int mi = 0; mi < 4; ++mi)
        #pragma unroll
        for (int ni = 0; ni < 2; ++ni)
          #pragma unroll
          for (int r4 = 0; r4 < 4; ++r4)
            sU[wm + mi * 16 + u2 * 4 + r4][ni * 16 + l15] = acc[mi][ni][r4];
    }
    __syncthreads();
    if (mat == 0) {
      #pragma unroll
      for (int mi = 0; mi < 4; ++mi)
        #pragma unroll
        for (int r4 = 0; r4 < 4; ++r4) {
          int mrow = wm + mi * 16 + u2 * 4 + r4;
          int m = m0 + mrow;
          if (m < n_e) {
            unsigned short* arow = act + (size_t)(off + m) * INNER + c * 32;
            #pragma unroll
            for (int ni = 0; ni < 2; ++ni) {
              int col = ni * 16 + l15;
              float g = acc[mi][ni][r4];
              float uu = sU[mrow][col];
              float ge = g / (1.0f + __expf(-1.5957691216057308f * (g + 0.044715f * g * g * g)));
              arow[col] = b16(ge * uu);
            }
          }
        }
    }
  }
}

// ---- phase 2: ybuf[p] = act[p] @ w2[e]^T ----
// 256 threads, tile 128M x 64N, BK=64, dbuf LDS 48KB -> 3 blocks/CU
// waves: wm = wave*32, all waves cover the full 64 N cols
__global__ __launch_bounds__(256, 3) void phase2_kernel(
    const unsigned short* __restrict__ act, const float* __restrict__ w2,
    const int* __restrict__ offsets, const int* __restrict__ counts,
    float* __restrict__ ybuf) {
  int c, e;
  decode_ce32(blockIdx.x, c, e);
  const int n_e = counts[e];
  if (n_e == 0) return;
  const int off = offsets[e];
  const int tid = threadIdx.x;
  const int lane = tid & 63, wave = tid >> 6;
  const int u2 = lane >> 4, l15 = lane & 15;
  const int wm = wave * 32;

  const int r16 = tid >> 4, l16 = tid & 15;
  const float* rp0 = w2 + ((size_t)e * HIDDEN + c * 64 + r16) * INNER;
  const float* rp1 = rp0 + (size_t)16 * INNER;
  const float* rp2 = rp0 + (size_t)32 * INNER;
  const float* rp3 = rp0 + (size_t)48 * INNER;
  const int bidx0 = r16 * 16 + (((l16 >> 1) ^ (r16 & 7)) << 1) + (l16 & 1);

  const int ar = tid >> 3, as = tid & 7;
  const int sxa = as ^ (ar & 7);

  __shared__ uint4 smem[2][1536];

  for (int m0 = 0; m0 < n_e; m0 += 128) {
    const unsigned short* a0 = act + (size_t)(off + (m0 + ar      < n_e ? m0 + ar      : n_e - 1)) * INNER;
    const unsigned short* a1 = act + (size_t)(off + (m0 + ar + 32 < n_e ? m0 + ar + 32 : n_e - 1)) * INNER;
    const unsigned short* a2 = act + (size_t)(off + (m0 + ar + 64 < n_e ? m0 + ar + 64 : n_e - 1)) * INNER;
    const unsigned short* a3 = act + (size_t)(off + (m0 + ar + 96 < n_e ? m0 + ar + 96 : n_e - 1)) * INNER;

    uint4 va0 = *((const uint4*)a0 + as);
    uint4 va1 = *((const uint4*)a1 + as);
    uint4 va2 = *((const uint4*)a2 + as);
    uint4 va3 = *((const uint4*)a3 + as);
    f32x4 vB0 = *((const f32x4*)rp0 + l16);
    f32x4 vB1 = *((const f32x4*)rp1 + l16);
    f32x4 vB2 = *((const f32x4*)rp2 + l16);
    f32x4 vB3 = *((const f32x4*)rp3 + l16);

    f32x4 acc[2][4];
    #pragma unroll
    for (int i = 0; i < 2; ++i)
      #pragma unroll
      for (int j = 0; j < 4; ++j) acc[i][j] = (f32x4)0.f;

    for (int k0 = 0; k0 < INNER; k0 += 64) {
      const int cur = (k0 >> 6) & 1;
      uint4* A = smem[cur];
      A[ar * 8 + sxa]          = va0;
      A[(ar + 32) * 8 + sxa]   = va1;
      A[(ar + 64) * 8 + sxa]   = va2;
      A[(ar + 96) * 8 + sxa]   = va3;
      {
        uint2* bb = (uint2*)(smem[cur] + 1024);
        bb[bidx0]       = make_uint2(pk2(vB0.x, vB0.y), pk2(vB0.z, vB0.w));
        bb[bidx0 + 256] = make_uint2(pk2(vB1.x, vB1.y), pk2(vB1.z, vB1.w));
        bb[bidx0 + 512] = make_uint2(pk2(vB2.x, vB2.y), pk2(vB2.z, vB2.w));
        bb[bidx0 + 768] = make_uint2(pk2(vB3.x, vB3.y), pk2(vB3.z, vB3.w));
      }
      __syncthreads();
      int k1 = k0 + 64;
      if (k1 < INNER) {
        va0 = *((const uint4*)(a0 + k1) + as);
        va1 = *((const uint4*)(a1 + k1) + as);
        va2 = *((const uint4*)(a2 + k1) + as);
        va3 = *((const uint4*)(a3 + k1) + as);
        vB0 = *((const f32x4*)(rp0 + k1) + l16);
        vB1 = *((const f32x4*)(rp1 + k1) + l16);
        vB2 = *((const f32x4*)(rp2 + k1) + l16);
        vB3 = *((const f32x4*)(rp3 + k1) + l16);
      }
      const uint4* Bq = smem[cur] + 1024;
      #pragma unroll
      for (int ks = 0; ks < 2; ++ks) {
        const int u = ks * 4 + u2;
        bf16x8 af[2], bfr[4];
        #pragma unroll
        for (int mi = 0; mi < 2; ++mi) {
          int r = wm + mi * 16 + l15;
          af[mi] = __builtin_bit_cast(bf16x8, A[r * 8 + (u ^ (r & 7))]);
        }
        #pragma unroll
        for (int ni = 0; ni < 4; ++ni) {
          int r = ni * 16 + l15;
          bfr[ni] = __builtin_bit_cast(bf16x8, Bq[r * 8 + (u ^ (r & 7))]);
        }
        #pragma unroll
        for (int mi = 0; mi < 2; ++mi)
          #pragma unroll
          for (int ni = 0; ni < 4; ++ni)
            acc[mi][ni] = __builtin_amdgcn_mfma_f32_16x16x32_bf16(af[mi], bfr[ni], acc[mi][ni], 0, 0, 0);
      }
    }

    #pragma unroll
    for (int mi = 0; mi < 2; ++mi)
      #pragma unroll
      for (int r4 = 0; r4 < 4; ++r4) {
        int mrow = wm + mi * 16 + u2 * 4 + r4;
        int m = m0 + mrow;
        if (m < n_e) {
          float* orow = ybuf + (size_t)(off + m) * HIDDEN + c * 64;
          #pragma unroll
          for (int ni = 0; ni < 4; ++ni)
            orow[ni * 16 + l15] = acc[mi][ni][r4];
        }
      }
    __syncthreads();
  }
}

// ---- combine: out[t] = sum_k w_k * ybuf[invpos[t,k]] ----
__global__ __launch_bounds__(256) void combine_kernel(const float* __restrict__ ybuf,
                                                      const int* __restrict__ invpos,
                                                      const float* __restrict__ topk_w,
                                                      float* __restrict__ out) {
  int t = blockIdx.x;
  int tid = threadIdx.x;
  int col = tid * 8;
  f32x4 a0 = (f32x4)0.f, a1 = (f32x4)0.f;
  #pragma unroll
  for (int k = 0; k < TOPK; ++k) {
    int p = invpos[t * TOPK + k];
    float w = topk_w[t * TOPK + k];
    const f32x4* yr = (const f32x4*)(ybuf + (size_t)p * HIDDEN + col);
    f32x4 v0 = yr[0], v1 = yr[1];
    a0 += w * v0;
    a1 += w * v1;
  }
  f32x4* o = (f32x4*)(out + (size_t)t * HIDDEN + col);
  o[0] = a0; o[1] = a1;
}

extern "C" void kernel_launch(void* const* d_in, const int* in_sizes, int n_in,
                              void* d_out, int out_size, void* d_ws, size_t ws_size,
                              hipStream_t stream) {
  const float* x  = (const float*)d_in[0];
  const float* gw = (const float*)d_in[1];
  const float* gb = (const float*)d_in[2];
  const float* w1 = (const float*)d_in[3];
  const float* w2 = (const float*)d_in[4];
  float* out = (float*)d_out;

  char* ws = (char*)d_ws;
  int*   ticket   = (int*)(ws + 0x000);
  int*   counts   = (int*)(ws + 0x100);
  int*   offsets  = (int*)(ws + 0x200);
  int*   topk_e   = (int*)(ws + 0x1000);
  float* topk_w   = (float*)(ws + 0x5000);
  int*   perm_tok = (int*)(ws + 0x9000);
  int*   invpos   = (int*)(ws + 0xD000);
  unsigned short* xb  = (unsigned short*)(ws + 0x11000);    // 2 MB
  unsigned short* act = (unsigned short*)(ws + 0x220000);   // 8 MB
  float* ybuf         = (float*)(ws + 0xA20000);            // 32 MB

  hipMemsetAsync(ticket, 0, 0x40, stream);

  gating_kernel<<<NTOK, 256, 0, stream>>>(x, gw, gb, ticket, counts, offsets,
                                          topk_e, topk_w, perm_tok, invpos, xb);
  phase1_kernel<<<2048, 256, 0, stream>>>(xb, w1, offsets, counts, perm_tok, act);
  phase2_kernel<<<2048, 256, 0, stream>>>(act, w2, offsets, counts, ybuf);
  combine_kernel<<<NTOK, 256, 0, stream>>>(ybuf, invpos, topk_w, out);
}

// Round 12
// 436.009 us; speedup vs baseline: 2.2187x; 1.0107x over previous
//
#include <hip/hip_runtime.h>
#include <hip/hip_bf16.h>

#define HIDDEN 2048
#define INNER  1024
#define NE     64
#define TOPK   8
#define NTOK   512

typedef float f32x4 __attribute__((ext_vector_type(4)));
typedef short bf16x8 __attribute__((ext_vector_type(8)));

static __device__ __forceinline__ unsigned short b16(float f) {
  return __builtin_bit_cast(unsigned short, __float2bfloat16(f));
}
static __device__ __forceinline__ unsigned int pk2(float lo, float hi) {
  return (unsigned)b16(lo) | ((unsigned)b16(hi) << 16);
}

// XCD-affinity decode for grid 2048: expert e -> XCD e&7.
static __device__ __forceinline__ void decode_ce32(int flat, int& c, int& e) {
  int xcd = flat & 7, s = flat >> 3;
  c = s & 31;
  e = ((s >> 5) << 3) | xcd;
}

// ---- gating: xconv + out-zero + gate dot + topk; last block does scan+scatter ----
__global__ __launch_bounds__(256) void gating_kernel(
    const float* __restrict__ x, const float* __restrict__ gw, const float* __restrict__ gb,
    int* __restrict__ ticket, int* __restrict__ counts, int* __restrict__ offsets,
    int* __restrict__ topk_e, float* __restrict__ topk_w,
    int* __restrict__ perm_tok, float* __restrict__ perm_wt,
    unsigned short* __restrict__ xb, float* __restrict__ out) {
  const int t = blockIdx.x;
  const int tid = threadIdx.x;
  const int lane = tid & 63, w = tid >> 6;

  {
    const float4* xi = (const float4*)(x + (size_t)t * HIDDEN);
    float4 v0 = xi[tid * 2], v1 = xi[tid * 2 + 1];
    ushort4 o0, o1;
    o0.x = b16(v0.x); o0.y = b16(v0.y); o0.z = b16(v0.z); o0.w = b16(v0.w);
    o1.x = b16(v1.x); o1.y = b16(v1.y); o1.z = b16(v1.z); o1.w = b16(v1.w);
    ushort4* xo = (ushort4*)(xb + (size_t)t * HIDDEN);
    xo[tid * 2] = o0; xo[tid * 2 + 1] = o1;
    f32x4 z = (f32x4)0.f;
    f32x4* orow = (f32x4*)(out + (size_t)t * HIDDEN);
    orow[tid * 2] = z; orow[tid * 2 + 1] = z;
  }

  const int e = tid >> 2, seg = tid & 3;
  const f32x4* gr = (const f32x4*)(gw + (size_t)e * HIDDEN);
  const f32x4* xr = (const f32x4*)(x + (size_t)t * HIDDEN);
  float acc = 0.f;
  #pragma unroll 8
  for (int k = 0; k < 128; ++k) {
    int idx = k * 4 + seg;
    f32x4 a = xr[idx], b = gr[idx];
    acc += a.x * b.x + a.y * b.y + a.z * b.z + a.w * b.w;
  }
  acc += __shfl_xor(acc, 1);
  acc += __shfl_xor(acc, 2);
  __shared__ float sP[NE];
  if (seg == 0) sP[e] = acc;
  __syncthreads();

  __shared__ float sW[TOPK];
  __shared__ int   sE[TOPK];
  if (w == 0) {
    float logit = gb[lane] + sP[lane];
    float m = logit;
    #pragma unroll
    for (int off = 32; off; off >>= 1) m = fmaxf(m, __shfl_xor(m, off));
    float p = __expf(logit - m);
    float s = p;
    #pragma unroll
    for (int off = 32; off; off >>= 1) s += __shfl_xor(s, off);
    p /= s;
    float myp = p;
    #pragma unroll
    for (int k = 0; k < TOPK; ++k) {
      float v = myp; int ei = lane;
      #pragma unroll
      for (int off = 32; off; off >>= 1) {
        float v2 = __shfl_xor(v, off); int e2 = __shfl_xor(ei, off);
        if (v2 > v || (v2 == v && e2 < ei)) { v = v2; ei = e2; }
      }
      if (lane == 0) { sW[k] = v; sE[k] = ei; }
      if (lane == ei) myp = -1.0f;
    }
  }
  __syncthreads();
  if (tid < TOPK) {
    float ss = 0.f;
    #pragma unroll
    for (int k = 0; k < TOPK; ++k) ss += sW[k];
    topk_e[t * TOPK + tid] = sE[tid];
    topk_w[t * TOPK + tid] = sW[tid] / ss;
  }

  __threadfence();
  __syncthreads();
  __shared__ int slast;
  if (tid == 0) {
    int old = atomicAdd(ticket, 1);
    slast = (old == (int)gridDim.x - 1);
  }
  __syncthreads();
  if (!slast) return;
  __threadfence();

  __shared__ int hcnt[NE], soff[NE], ccur[NE];
  if (tid < NE) hcnt[tid] = 0;
  __syncthreads();
  for (int i = tid; i < NTOK * TOPK; i += 256) atomicAdd(&hcnt[topk_e[i]], 1);
  __syncthreads();
  if (tid < NE) {
    int c = hcnt[tid];
    int s = c;
    #pragma unroll
    for (int off = 1; off < 64; off <<= 1) {
      int o = __shfl_up(s, off);
      if (tid >= off) s += o;
    }
    soff[tid] = s - c; ccur[tid] = 0;
    counts[tid] = c; offsets[tid] = s - c;
  }
  __syncthreads();
  for (int i = tid; i < NTOK * TOPK; i += 256) {
    int ee = topk_e[i];
    int p = atomicAdd(&ccur[ee], 1);
    int pos = soff[ee] + p;
    perm_tok[pos] = i >> 3;
    perm_wt[pos] = topk_w[i];
  }
}

// ---- phase 1: act = gelu(x@w1g^T) * (x@w1u^T) ----
// 256 threads, tile 128M x 32N(gate)+32N(up), BK=64, dbuf LDS 48KB -> 3 blocks/CU
__global__ __launch_bounds__(256, 3) void phase1_kernel(
    const unsigned short* __restrict__ xb, const float* __restrict__ w1,
    const int* __restrict__ offsets, const int* __restrict__ counts,
    const int* __restrict__ perm_tok, unsigned short* __restrict__ act) {
  int c, e;
  decode_ce32(blockIdx.x, c, e);
  const int n_e = counts[e];
  if (n_e == 0) return;
  const int off = offsets[e];
  const int tid = threadIdx.x;
  const int lane = tid & 63, wave = tid >> 6;
  const int u2 = lane >> 4, l15 = lane & 15;
  const int mat = wave >> 1;
  const int wm  = (wave & 1) * 64;

  const int r16 = tid >> 4, l16 = tid & 15;
  const float* wg  = w1 + (size_t)e * (2 * INNER) * HIDDEN;
  const float* rp0 = wg + (size_t)(c * 32 + r16) * HIDDEN;
  const float* rp1 = rp0 + (size_t)16 * HIDDEN;
  const float* rp2 = wg + (size_t)(INNER + c * 32 + r16) * HIDDEN;
  const float* rp3 = rp2 + (size_t)16 * HIDDEN;
  const int bidx0 = r16 * 16 + (((l16 >> 1) ^ (r16 & 7)) << 1) + (l16 & 1);

  const int ar = tid >> 3, as = tid & 7;
  const int sxa = as ^ (ar & 7);

  __shared__ uint4 smem[2][1536];
  __shared__ int stok[128];
  float (*sU)[36] = (float(*)[36])&smem[0][0];

  for (int m0 = 0; m0 < n_e; m0 += 128) {
    __syncthreads();
    if (tid < 128) {
      int idx = m0 + tid;
      stok[tid] = perm_tok[off + (idx < n_e ? idx : n_e - 1)];
    }
    __syncthreads();

    const unsigned short* xr0 = xb + (size_t)stok[ar] * HIDDEN;
    const unsigned short* xr1 = xb + (size_t)stok[ar + 32] * HIDDEN;
    const unsigned short* xr2 = xb + (size_t)stok[ar + 64] * HIDDEN;
    const unsigned short* xr3 = xb + (size_t)stok[ar + 96] * HIDDEN;

    uint4 va0 = *((const uint4*)xr0 + as);
    uint4 va1 = *((const uint4*)xr1 + as);
    uint4 va2 = *((const uint4*)xr2 + as);
    uint4 va3 = *((const uint4*)xr3 + as);
    f32x4 vB0 = *((const f32x4*)rp0 + l16);
    f32x4 vB1 = *((const f32x4*)rp1 + l16);
    f32x4 vB2 = *((const f32x4*)rp2 + l16);
    f32x4 vB3 = *((const f32x4*)rp3 + l16);

    f32x4 acc[4][2];
    #pragma unroll
    for (int i = 0; i < 4; ++i)
      #pragma unroll
      for (int j = 0; j < 2; ++j) acc[i][j] = (f32x4)0.f;

    for (int k0 = 0; k0 < HIDDEN; k0 += 64) {
      const int cur = (k0 >> 6) & 1;
      uint4* A = smem[cur];
      A[ar * 8 + sxa]          = va0;
      A[(ar + 32) * 8 + sxa]   = va1;
      A[(ar + 64) * 8 + sxa]   = va2;
      A[(ar + 96) * 8 + sxa]   = va3;
      {
        uint2* bb = (uint2*)(smem[cur] + 1024);
        bb[bidx0]       = make_uint2(pk2(vB0.x, vB0.y), pk2(vB0.z, vB0.w));
        bb[bidx0 + 256] = make_uint2(pk2(vB1.x, vB1.y), pk2(vB1.z, vB1.w));
        bb[bidx0 + 512] = make_uint2(pk2(vB2.x, vB2.y), pk2(vB2.z, vB2.w));
        bb[bidx0 + 768] = make_uint2(pk2(vB3.x, vB3.y), pk2(vB3.z, vB3.w));
      }
      __syncthreads();
      int k1 = k0 + 64;
      if (k1 < HIDDEN) {
        va0 = *((const uint4*)(xr0 + k1) + as);
        va1 = *((const uint4*)(xr1 + k1) + as);
        va2 = *((const uint4*)(xr2 + k1) + as);
        va3 = *((const uint4*)(xr3 + k1) + as);
        vB0 = *((const f32x4*)(rp0 + k1) + l16);
        vB1 = *((const f32x4*)(rp1 + k1) + l16);
        vB2 = *((const f32x4*)(rp2 + k1) + l16);
        vB3 = *((const f32x4*)(rp3 + k1) + l16);
      }
      const uint4* Bq = smem[cur] + 1024;
      #pragma unroll
      for (int ks = 0; ks < 2; ++ks) {
        const int u = ks * 4 + u2;
        bf16x8 af[4], bfr[2];
        #pragma unroll
        for (int mi = 0; mi < 4; ++mi) {
          int r = wm + mi * 16 + l15;
          af[mi] = __builtin_bit_cast(bf16x8, A[r * 8 + (u ^ (r & 7))]);
        }
        #pragma unroll
        for (int ni = 0; ni < 2; ++ni) {
          int r = mat * 32 + ni * 16 + l15;
          bfr[ni] = __builtin_bit_cast(bf16x8, Bq[r * 8 + (u ^ (r & 7))]);
        }
        #pragma unroll
        for (int mi = 0; mi < 4; ++mi)
          #pragma unroll
          for (int ni = 0; ni < 2; ++ni)
            acc[mi][ni] = __builtin_amdgcn_mfma_f32_16x16x32_bf16(af[mi], bfr[ni], acc[mi][ni], 0, 0, 0);
      }
    }

    __syncthreads();
    if (mat == 1) {
      #pragma unroll
      for (int mi = 0; mi < 4; ++mi)
        #pragma unroll
        for (int ni = 0; ni < 2; ++ni)
          #pragma unroll
          for (int r4 = 0; r4 < 4; ++r4)
            sU[wm + mi * 16 + u2 * 4 + r4][ni * 16 + l15] = acc[mi][ni][r4];
    }
    __syncthreads();
    if (mat == 0) {
      #pragma unroll
      for (int mi = 0; mi < 4; ++mi)
        #pragma unroll
        for (int r4 = 0; r4 < 4; ++r4) {
          int mrow = wm + mi * 16 + u2 * 4 + r4;
          int m = m0 + mrow;
          if (m < n_e) {
            unsigned short* arow = act + (size_t)(off + m) * INNER + c * 32;
            #pragma unroll
            for (int ni = 0; ni < 2; ++ni) {
              int col = ni * 16 + l15;
              float g = acc[mi][ni][r4];
              float uu = sU[mrow][col];
              float ge = g / (1.0f + __expf(-1.5957691216057308f * (g + 0.044715f * g * g * g)));
              arow[col] = b16(ge * uu);
            }
          }
        }
    }
  }
}

// ---- phase 2: out[tok] += wt * (act @ w2[e]^T), atomic epilogue ----
// 256 threads, tile 128M x 64N, BK=64, dbuf LDS 48KB -> 3 blocks/CU
__global__ __launch_bounds__(256, 3) void phase2_kernel(
    const unsigned short* __restrict__ act, const float* __restrict__ w2,
    const int* __restrict__ offsets, const int* __restrict__ counts,
    const int* __restrict__ perm_tok, const float* __restrict__ perm_wt,
    float* __restrict__ out) {
  int c, e;
  decode_ce32(blockIdx.x, c, e);
  const int n_e = counts[e];
  if (n_e == 0) return;
  const int off = offsets[e];
  const int tid = threadIdx.x;
  const int lane = tid & 63, wave = tid >> 6;
  const int u2 = lane >> 4, l15 = lane & 15;
  const int wm = wave * 32;

  const int r16 = tid >> 4, l16 = tid & 15;
  const float* rp0 = w2 + ((size_t)e * HIDDEN + c * 64 + r16) * INNER;
  const float* rp1 = rp0 + (size_t)16 * INNER;
  const float* rp2 = rp0 + (size_t)32 * INNER;
  const float* rp3 = rp0 + (size_t)48 * INNER;
  const int bidx0 = r16 * 16 + (((l16 >> 1) ^ (r16 & 7)) << 1) + (l16 & 1);

  const int ar = tid >> 3, as = tid & 7;
  const int sxa = as ^ (ar & 7);

  __shared__ uint4 smem[2][1536];
  __shared__ int   stok[128];
  __shared__ float swt[128];

  for (int m0 = 0; m0 < n_e; m0 += 128) {
    __syncthreads();
    if (tid < 128) {
      int idx = m0 + tid;
      int cl = idx < n_e ? idx : n_e - 1;
      stok[tid] = perm_tok[off + cl];
      swt[tid] = (idx < n_e) ? perm_wt[off + cl] : 0.f;
    }
    __syncthreads();

    const unsigned short* a0 = act + (size_t)(off + (m0 + ar      < n_e ? m0 + ar      : n_e - 1)) * INNER;
    const unsigned short* a1 = act + (size_t)(off + (m0 + ar + 32 < n_e ? m0 + ar + 32 : n_e - 1)) * INNER;
    const unsigned short* a2 = act + (size_t)(off + (m0 + ar + 64 < n_e ? m0 + ar + 64 : n_e - 1)) * INNER;
    const unsigned short* a3 = act + (size_t)(off + (m0 + ar + 96 < n_e ? m0 + ar + 96 : n_e - 1)) * INNER;

    uint4 va0 = *((const uint4*)a0 + as);
    uint4 va1 = *((const uint4*)a1 + as);
    uint4 va2 = *((const uint4*)a2 + as);
    uint4 va3 = *((const uint4*)a3 + as);
    f32x4 vB0 = *((const f32x4*)rp0 + l16);
    f32x4 vB1 = *((const f32x4*)rp1 + l16);
    f32x4 vB2 = *((const f32x4*)rp2 + l16);
    f32x4 vB3 = *((const f32x4*)rp3 + l16);

    f32x4 acc[2][4];
    #pragma unroll
    for (int i = 0; i < 2; ++i)
      #pragma unroll
      for (int j = 0; j < 4; ++j) acc[i][j] = (f32x4)0.f;

    for (int k0 = 0; k0 < INNER; k0 += 64) {
      const int cur = (k0 >> 6) & 1;
      uint4* A = smem[cur];
      A[ar * 8 + sxa]          = va0;
      A[(ar + 32) * 8 + sxa]   = va1;
      A[(ar + 64) * 8 + sxa]   = va2;
      A[(ar + 96) * 8 + sxa]   = va3;
      {
        uint2* bb = (uint2*)(smem[cur] + 1024);
        bb[bidx0]       = make_uint2(pk2(vB0.x, vB0.y), pk2(vB0.z, vB0.w));
        bb[bidx0 + 256] = make_uint2(pk2(vB1.x, vB1.y), pk2(vB1.z, vB1.w));
        bb[bidx0 + 512] = make_uint2(pk2(vB2.x, vB2.y), pk2(vB2.z, vB2.w));
        bb[bidx0 + 768] = make_uint2(pk2(vB3.x, vB3.y), pk2(vB3.z, vB3.w));
      }
      __syncthreads();
      int k1 = k0 + 64;
      if (k1 < INNER) {
        va0 = *((const uint4*)(a0 + k1) + as);
        va1 = *((const uint4*)(a1 + k1) + as);
        va2 = *((const uint4*)(a2 + k1) + as);
        va3 = *((const uint4*)(a3 + k1) + as);
        vB0 = *((const f32x4*)(rp0 + k1) + l16);
        vB1 = *((const f32x4*)(rp1 + k1) + l16);
        vB2 = *((const f32x4*)(rp2 + k1) + l16);
        vB3 = *((const f32x4*)(rp3 + k1) + l16);
      }
      const uint4* Bq = smem[cur] + 1024;
      #pragma unroll
      for (int ks = 0; ks < 2; ++ks) {
        const int u = ks * 4 + u2;
        bf16x8 af[2], bfr[4];
        #pragma unroll
        for (int mi = 0; mi < 2; ++mi) {
          int r = wm + mi * 16 + l15;
          af[mi] = __builtin_bit_cast(bf16x8, A[r * 8 + (u ^ (r & 7))]);
        }
        #pragma unroll
        for (int ni = 0; ni < 4; ++ni) {
          int r = ni * 16 + l15;
          bfr[ni] = __builtin_bit_cast(bf16x8, Bq[r * 8 + (u ^ (r & 7))]);
        }
        #pragma unroll
        for (int mi = 0; mi < 2; ++mi)
          #pragma unroll
          for (int ni = 0; ni < 4; ++ni)
            acc[mi][ni] = __builtin_amdgcn_mfma_f32_16x16x32_bf16(af[mi], bfr[ni], acc[mi][ni], 0, 0, 0);
      }
    }

    #pragma unroll
    for (int mi = 0; mi < 2; ++mi)
      #pragma unroll
      for (int r4 = 0; r4 < 4; ++r4) {
        int mrow = wm + mi * 16 + u2 * 4 + r4;
        int m = m0 + mrow;
        if (m < n_e) {
          int tok = stok[mrow];
          float wt = swt[mrow];
          float* orow = out + (size_t)tok * HIDDEN + c * 64;
          #pragma unroll
          for (int ni = 0; ni < 4; ++ni)
            atomicAdd(&orow[ni * 16 + l15], wt * acc[mi][ni][r4]);
        }
      }
    __syncthreads();
  }
}

extern "C" void kernel_launch(void* const* d_in, const int* in_sizes, int n_in,
                              void* d_out, int out_size, void* d_ws, size_t ws_size,
                              hipStream_t stream) {
  const float* x  = (const float*)d_in[0];
  const float* gw = (const float*)d_in[1];
  const float* gb = (const float*)d_in[2];
  const float* w1 = (const float*)d_in[3];
  const float* w2 = (const float*)d_in[4];
  float* out = (float*)d_out;

  char* ws = (char*)d_ws;
  int*   ticket   = (int*)(ws + 0x000);
  int*   counts   = (int*)(ws + 0x100);
  int*   offsets  = (int*)(ws + 0x200);
  int*   topk_e   = (int*)(ws + 0x1000);
  float* topk_w   = (float*)(ws + 0x5000);
  int*   perm_tok = (int*)(ws + 0x9000);
  float* perm_wt  = (float*)(ws + 0xD000);
  unsigned short* xb  = (unsigned short*)(ws + 0x11000);    // 2 MB
  unsigned short* act = (unsigned short*)(ws + 0x220000);   // 8 MB

  hipMemsetAsync(ticket, 0, 0x40, stream);

  gating_kernel<<<NTOK, 256, 0, stream>>>(x, gw, gb, ticket, counts, offsets,
                                          topk_e, topk_w, perm_tok, perm_wt, xb, out);
  phase1_kernel<<<2048, 256, 0, stream>>>(xb, w1, offsets, counts, perm_tok, act);
  phase2_kernel<<<2048, 256, 0, stream>>>(act, w2, offsets, counts, perm_tok, perm_wt, out);
}